// Round 3
// baseline (671.968 us; speedup 1.0000x reference)
//
#include <hip/hip_runtime.h>
#include <hip/hip_bf16.h>

// Problem constants (fixed by the reference)
#define VOCAB 50000
#define D     300
#define B_    64
#define LC    32
#define T_    256
#define LT    64
#define NSEL  5

// A-image geometry: 32 rows x 40 slots (16B = 8 f16), k padded 300->320,
// slot s stored at s ^ (m&7) -> conflict-free ds_read_b128.
// hi: uint4[0..1280), lo: uint4[1280..2560). 40960 B per batch.
#define A_U4   2560
#define A_HALF 20480
#define TROW   640            // interleaved row: hi [0,320) | lo [320,640) halfs (1280 B)

typedef _Float16 half8_t __attribute__((ext_vector_type(8)));
typedef float    f32x4   __attribute__((ext_vector_type(4)));

// ---------------- K0: merged prep: table (hi|lo f16) + claim images ----------
__global__ __launch_bounds__(256) void k_prep(const int* __restrict__ claim,
                                              const float* __restrict__ emb,
                                              _Float16* __restrict__ tab,
                                              _Float16* __restrict__ wsA,
                                              int tableBlocks) {
    int wave = threadIdx.x >> 6, lane = threadIdx.x & 63;
    if ((int)blockIdx.x < tableBlocks) {
        int r = blockIdx.x * 4 + wave;               // 12500*4 = 50000 rows
        const float* src = emb + (size_t)r * D;
        _Float16* d = tab + (size_t)r * TROW;
#pragma unroll
        for (int i = 0; i < 5; ++i) {
            int k = lane + i * 64;
            float x = (k < D) ? src[k] : 0.0f;
            _Float16 h = (_Float16)x;
            d[k] = h;
            d[320 + k] = (_Float16)(x - (float)h);
        }
    } else {
        int row = (blockIdx.x - tableBlocks) * 4 + wave;   // 0..2047
        int b = row >> 5, m = row & 31;
        int tok = claim[row];
        const float* src = emb + (size_t)tok * D;
        _Float16* base = wsA + (size_t)b * A_HALF;
#pragma unroll
        for (int i = 0; i < 5; ++i) {
            int k = lane + i * 64;
            float x = (k < D) ? src[k] : 0.0f;
            _Float16 h = (_Float16)x;
            int sp = ((k >> 3) ^ (m & 7));
            int idx = (m * 40 + sp) * 8 + (k & 7);
            base[idx] = h;
            base[10240 + idx] = (_Float16)(x - (float)h);
        }
    }
}

// hi/lo split of a float4 pair into half8 hi and half8 lo (slow path only)
__device__ __forceinline__ void split8(const float4& a, const float4& b,
                                       half8_t& hv, half8_t& lv) {
    float x[8] = {a.x, a.y, a.z, a.w, b.x, b.y, b.z, b.w};
#pragma unroll
    for (int i = 0; i < 8; ++i) {
        _Float16 h = (_Float16)x[i];
        hv[i] = h;
        lv[i] = (_Float16)(x[i] - (float)h);
    }
}

// ---------------- shared K-loop: U tile via f16x2-split MFMA ------------------
// acc[mi][ni] covers c = mi*16+quad*4+reg, l = lcol0 + ni*16 + ln.
// FAST: depth-2 double-buffered B loads from f16 hi|lo interleaved table.
// NOTE (R1): depth-3 spilled (FETCH +0.58 GB, WRITE +0.30 GB, 185->411us).
// NOTE (R2): setprio(1) around MFMAs cost +4% (lockstep-identical waves, T5
// null regime) — removed.
template<bool FAST, int NI>
__device__ __forceinline__ void compute_U(const uint4* sA,
                                          const float* __restrict__ emb,
                                          const _Float16* __restrict__ tab,
                                          const int* __restrict__ trow, int lcol0,
                                          int lane, f32x4 acc[2][NI]) {
    int ln = lane & 15, quad = lane >> 4;
#pragma unroll
    for (int mi = 0; mi < 2; ++mi)
#pragma unroll
        for (int ni = 0; ni < NI; ++ni) acc[mi][ni] = (f32x4)0.0f;

    int arow0 = ln * 40;            // m = ln      (mi=0)
    int arow1 = (16 + ln) * 40;     // m = 16+ln   (mi=1)
    int key = ln & 7;
    int qo = quad * 8;

    if (FAST) {
        const _Float16* rp[NI];
#pragma unroll
        for (int ni = 0; ni < NI; ++ni) {
            int tok = trow[lcol0 + ni * 16 + ln];
            rp[ni] = tab + (size_t)tok * TROW;
        }
        // depth-2 pipeline: hi half8 + lo half8 double-buffered, base+imm loads.
        half8_t bh[2][NI], bl[2][NI];
#pragma unroll
        for (int ni = 0; ni < NI; ++ni) {
            bh[0][ni] = *(const half8_t*)(rp[ni] + qo);
            bl[0][ni] = *(const half8_t*)(rp[ni] + 320 + qo);
        }
#pragma unroll
        for (int ks = 0; ks < 10; ++ks) {
            int cur = ks & 1, nxt = cur ^ 1;
            if (ks < 9) {
                int ko = (ks + 1) * 32 + qo;
#pragma unroll
                for (int ni = 0; ni < NI; ++ni) {
                    bh[nxt][ni] = *(const half8_t*)(rp[ni] + ko);
                    bl[nxt][ni] = *(const half8_t*)(rp[ni] + 320 + ko);
                }
            }
            int sp = (ks * 4 + quad) ^ key;
            half8_t ah[2], al[2];
            ah[0] = __builtin_bit_cast(half8_t, sA[arow0 + sp]);
            al[0] = __builtin_bit_cast(half8_t, sA[1280 + arow0 + sp]);
            ah[1] = __builtin_bit_cast(half8_t, sA[arow1 + sp]);
            al[1] = __builtin_bit_cast(half8_t, sA[1280 + arow1 + sp]);
#pragma unroll
            for (int mi = 0; mi < 2; ++mi)
#pragma unroll
                for (int ni = 0; ni < NI; ++ni) {
                    acc[mi][ni] = __builtin_amdgcn_mfma_f32_16x16x32_f16(ah[mi], bh[cur][ni], acc[mi][ni], 0, 0, 0);
                    acc[mi][ni] = __builtin_amdgcn_mfma_f32_16x16x32_f16(ah[mi], bl[cur][ni], acc[mi][ni], 0, 0, 0);
                    acc[mi][ni] = __builtin_amdgcn_mfma_f32_16x16x32_f16(al[mi], bh[cur][ni], acc[mi][ni], 0, 0, 0);
                }
        }
    } else {
        const float* bp[NI];
#pragma unroll
        for (int ni = 0; ni < NI; ++ni) {
            int tok = trow[lcol0 + ni * 16 + ln];
            bp[ni] = emb + (size_t)tok * D;
        }
#pragma unroll 1
        for (int ks = 0; ks < 10; ++ks) {
            int kb = ks * 32 + qo;
            int ka = kb > 296 ? 296 : kb;
            int kb4 = kb + 4;
            int kbb = kb4 > 296 ? 296 : kb4;
            float4 b0[NI], b1[NI];
#pragma unroll
            for (int ni = 0; ni < NI; ++ni) {
                b0[ni] = *(const float4*)(bp[ni] + ka);
                b1[ni] = *(const float4*)(bp[ni] + kbb);
            }
            if (kb >= 296) {
                float4 z = make_float4(0.f, 0.f, 0.f, 0.f);
#pragma unroll
                for (int ni = 0; ni < NI; ++ni) {
                    if (kb >= 300) b0[ni] = z;
                    b1[ni] = z;
                }
            }
            int sp = (ks * 4 + quad) ^ key;
            half8_t ah[2], al[2];
            ah[0] = __builtin_bit_cast(half8_t, sA[arow0 + sp]);
            al[0] = __builtin_bit_cast(half8_t, sA[1280 + arow0 + sp]);
            ah[1] = __builtin_bit_cast(half8_t, sA[arow1 + sp]);
            al[1] = __builtin_bit_cast(half8_t, sA[1280 + arow1 + sp]);
            half8_t bh[NI], bl[NI];
#pragma unroll
            for (int ni = 0; ni < NI; ++ni) split8(b0[ni], b1[ni], bh[ni], bl[ni]);
#pragma unroll
            for (int mi = 0; mi < 2; ++mi)
#pragma unroll
                for (int ni = 0; ni < NI; ++ni) {
                    acc[mi][ni] = __builtin_amdgcn_mfma_f32_16x16x32_f16(ah[mi], bh[ni], acc[mi][ni], 0, 0, 0);
                    acc[mi][ni] = __builtin_amdgcn_mfma_f32_16x16x32_f16(ah[mi], bl[ni], acc[mi][ni], 0, 0, 0);
                    acc[mi][ni] = __builtin_amdgcn_mfma_f32_16x16x32_f16(al[mi], bh[ni], acc[mi][ni], 0, 0, 0);
                }
        }
    }
}

__device__ __forceinline__ float xmax4(float v) {
    v = fmaxf(v, __shfl_xor(v, 1)); v = fmaxf(v, __shfl_xor(v, 2));
    v = fmaxf(v, __shfl_xor(v, 4)); v = fmaxf(v, __shfl_xor(v, 8));
    return v;
}
__device__ __forceinline__ float xsum4(float v) {
    v += __shfl_xor(v, 1); v += __shfl_xor(v, 2);
    v += __shfl_xor(v, 4); v += __shfl_xor(v, 8);
    return v;
}

// ---------------- K2: target scores (8 waves/block share one sA image) ------
// 512-thread blocks double waves/CU 16->32 (LDS 4x40KB = 160KB exactly):
// doubles in-flight gather instructions per CU (the R2 theory: MLP-bound).
// Grid 2048: xcd = wg&7, b = xcd*8 + (rest>>5), tg = rest&31, t = tg*8+wave.
template<bool FAST>
__global__ __launch_bounds__(512, 8) void k_scores(const int* __restrict__ targets,
                                                   const float* __restrict__ emb,
                                                   const _Float16* __restrict__ tab,
                                                   const _Float16* __restrict__ wsA,
                                                   float* __restrict__ wsScr) {
    __shared__ __align__(16) uint4 sA[A_U4];   // 40960 B -> 4 blocks/CU
    int wg = blockIdx.x;
    int xcd = wg & 7, rest = wg >> 3;
    int b = xcd * 8 + (rest >> 5);
    int tg = rest & 31;
    int tid = threadIdx.x;
    {
        const uint4* src = (const uint4*)(wsA + (size_t)b * A_HALF);
        for (int i = tid; i < A_U4; i += 512) sA[i] = src[i];
    }
    __syncthreads();

    int lane = tid & 63, wave = tid >> 6;
    int t = tg * 8 + wave;
    const int* trow = targets + ((size_t)b * T_ + t) * LT;

    f32x4 acc[2][4];
    compute_U<FAST, 4>(sA, emb, tab, trow, 0, lane, acc);

    // softmax over l per c, max over c, sum over l — all in-wave
    float score_l[4] = {0.f, 0.f, 0.f, 0.f};
#pragma unroll
    for (int mi = 0; mi < 2; ++mi)
#pragma unroll
        for (int r = 0; r < 4; ++r) {
            float m = fmaxf(fmaxf(acc[mi][0][r], acc[mi][1][r]),
                            fmaxf(acc[mi][2][r], acc[mi][3][r]));
            m = xmax4(m);                     // max over 64 l for this c
            float p[4], s = 0.f;
#pragma unroll
            for (int ni = 0; ni < 4; ++ni) { p[ni] = __expf(acc[mi][ni][r] - m); s += p[ni]; }
            s = xsum4(s);                     // denom over 64 l
            float rv = 1.0f / s;
#pragma unroll
            for (int ni = 0; ni < 4; ++ni) score_l[ni] = fmaxf(score_l[ni], p[ni] * rv);
        }
    float tot = 0.f;
#pragma unroll
    for (int ni = 0; ni < 4; ++ni) {
        float v = score_l[ni];                // fold max over c across quads
        v = fmaxf(v, __shfl_xor(v, 16));
        v = fmaxf(v, __shfl_xor(v, 32));
        tot += v;
    }
    tot = xsum4(tot);                         // sum over the 16 ln-columns
    if (lane == 0) wsScr[b * T_ + t] = tot;
}

// ---------------- K4: top-j select + recompute selected tile, L2-normalize ---
// One 256-thread block per (b, j). Wave 0 replays the top-k selection from
// wsScr (descending, lowest-index ties) while waves 1..3 stage the claim image.
template<bool FAST>
__global__ __launch_bounds__(256) void k_output(const int* __restrict__ targets,
                                                const float* __restrict__ emb,
                                                const _Float16* __restrict__ tab,
                                                const _Float16* __restrict__ wsA,
                                                const float* __restrict__ wsScr,
                                                float* __restrict__ out) {
    __shared__ __align__(16) uint4 sA[A_U4];
    __shared__ float sS[LC][4];
    __shared__ int sT;
    int b = blockIdx.y, j = blockIdx.x, tid = threadIdx.x;
    int lane = tid & 63, wave = tid >> 6;
    if (wave) {
        const uint4* src = (const uint4*)(wsA + (size_t)b * A_HALF);
        for (int i = tid - 64; i < A_U4; i += 192) sA[i] = src[i];
    } else {
        float v[4];
#pragma unroll
        for (int i = 0; i < 4; ++i) v[i] = wsScr[b * T_ + lane + 64 * i];
        int sel = 0;
        for (int r = 0; r <= j; ++r) {
            float bv = v[0]; int bi = lane;
#pragma unroll
            for (int i = 1; i < 4; ++i) {
                int idx = lane + 64 * i;
                if (v[i] > bv) { bv = v[i]; bi = idx; }
            }
            for (int off = 32; off > 0; off >>= 1) {
                float ov = __shfl_down(bv, off);
                int   oi = __shfl_down(bi, off);
                if (ov > bv || (ov == bv && oi < bi)) { bv = ov; bi = oi; }
            }
            bi = __shfl(bi, 0);
            sel = bi;
            if ((bi & 63) == lane) v[bi >> 6] = -1e30f;   // remove winner
        }
        if (lane == 0) sT = sel;
    }
    __syncthreads();

    int t = sT;
    const int* trow = targets + ((size_t)b * T_ + t) * LT;
    f32x4 acc[2][1];
    compute_U<FAST, 1>(sA, emb, tab, trow, wave * 16, lane, acc);

    int ln = lane & 15, quad = lane >> 4;
    // partial sum of squares over this wave's 16 l's, per c
#pragma unroll
    for (int mi = 0; mi < 2; ++mi)
#pragma unroll
        for (int r = 0; r < 4; ++r) {
            float v = acc[mi][0][r] * acc[mi][0][r];
            v = xsum4(v);                       // sum over the 16 ln-columns
            if (ln == 0) sS[mi * 16 + quad * 4 + r][wave] = v;
        }
    __syncthreads();

    float* obase = out + (size_t)(b * NSEL + j) * (LC * LT);
#pragma unroll
    for (int mi = 0; mi < 2; ++mi)
#pragma unroll
        for (int r = 0; r < 4; ++r) {
            int c = mi * 16 + quad * 4 + r;
            float ss = sS[c][0] + sS[c][1] + sS[c][2] + sS[c][3];
            float rinv = 1.0f / sqrtf(ss);
            obase[c * LT + wave * 16 + ln] = acc[mi][0][r] * rinv;
        }
}

extern "C" void kernel_launch(void* const* d_in, const int* in_sizes, int n_in,
                              void* d_out, int out_size, void* d_ws, size_t ws_size,
                              hipStream_t stream) {
    const int*   claim   = (const int*)d_in[0];
    const int*   targets = (const int*)d_in[1];
    const float* emb     = (const float*)d_in[2];
    // d_in[3] is n (=5), compile-time NSEL

    const size_t tabBytes = (size_t)VOCAB * TROW * sizeof(_Float16);   // 64 MB
    const size_t restBytes = (size_t)B_ * A_HALF * sizeof(_Float16)
                           + (size_t)B_ * T_ * sizeof(float)
                           + (size_t)B_ * NSEL * sizeof(int) + 256;
    bool fast = ws_size >= tabBytes + restBytes;   // deterministic per run

    char* p = (char*)d_ws;
    _Float16* tab = nullptr;
    if (fast) { tab = (_Float16*)p; p += tabBytes; }
    _Float16* wsA = (_Float16*)p; p += (size_t)B_ * A_HALF * sizeof(_Float16);
    float* wsScr = (float*)p;
    float* out   = (float*)d_out;

    int tableBlocks = fast ? (VOCAB / 4) : 0;
    k_prep<<<dim3(tableBlocks + 512), dim3(256), 0, stream>>>(claim, emb, tab, wsA, tableBlocks);
    if (fast) {
        k_scores<true><<<dim3(B_ * 32), dim3(512), 0, stream>>>(targets, emb, tab, wsA, wsScr);
        k_output<true><<<dim3(NSEL, B_), dim3(256), 0, stream>>>(targets, emb, tab, wsA, wsScr, out);
    } else {
        k_scores<false><<<dim3(B_ * 32), dim3(512), 0, stream>>>(targets, emb, tab, wsA, wsScr);
        k_output<false><<<dim3(NSEL, B_), dim3(256), 0, stream>>>(targets, emb, tab, wsA, wsScr, out);
    }
}

// Round 5
// 530.288 us; speedup vs baseline: 1.2672x; 1.2672x over previous
//
#include <hip/hip_runtime.h>
#include <hip/hip_bf16.h>

// Problem constants (fixed by the reference)
#define VOCAB 50000
#define D     300
#define B_    64
#define LC    32
#define T_    256
#define LT    64
#define NSEL  5

// A-image geometry: 32 rows x 40 slots (16B = 8 f16), k padded 300->320,
// slot s stored at s ^ (m&7) -> conflict-free ds_read_b128.
// hi: uint4[0..1280), lo: uint4[1280..2560). 40960 B per batch.
#define A_U4   2560
#define A_HALF 20480
#define TROW   640            // interleaved row: hi [0,320) | lo [320,640) halfs (1280 B)

typedef _Float16 half8_t __attribute__((ext_vector_type(8)));
typedef float    f32x4   __attribute__((ext_vector_type(4)));

// ---------------- K0: merged prep: table (hi|lo f16) + claim images ----------
__global__ __launch_bounds__(256) void k_prep(const int* __restrict__ claim,
                                              const float* __restrict__ emb,
                                              _Float16* __restrict__ tab,
                                              _Float16* __restrict__ wsA,
                                              int tableBlocks) {
    int wave = threadIdx.x >> 6, lane = threadIdx.x & 63;
    if ((int)blockIdx.x < tableBlocks) {
        int r = blockIdx.x * 4 + wave;               // 12500*4 = 50000 rows
        const float* src = emb + (size_t)r * D;
        _Float16* d = tab + (size_t)r * TROW;
#pragma unroll
        for (int i = 0; i < 5; ++i) {
            int k = lane + i * 64;
            float x = (k < D) ? src[k] : 0.0f;
            _Float16 h = (_Float16)x;
            d[k] = h;
            d[320 + k] = (_Float16)(x - (float)h);
        }
    } else {
        int row = (blockIdx.x - tableBlocks) * 4 + wave;   // 0..2047
        int b = row >> 5, m = row & 31;
        int tok = claim[row];
        const float* src = emb + (size_t)tok * D;
        _Float16* base = wsA + (size_t)b * A_HALF;
#pragma unroll
        for (int i = 0; i < 5; ++i) {
            int k = lane + i * 64;
            float x = (k < D) ? src[k] : 0.0f;
            _Float16 h = (_Float16)x;
            int sp = ((k >> 3) ^ (m & 7));
            int idx = (m * 40 + sp) * 8 + (k & 7);
            base[idx] = h;
            base[10240 + idx] = (_Float16)(x - (float)h);
        }
    }
}

// hi/lo split of a float4 pair into half8 hi and half8 lo (slow path only)
__device__ __forceinline__ void split8(const float4& a, const float4& b,
                                       half8_t& hv, half8_t& lv) {
    float x[8] = {a.x, a.y, a.z, a.w, b.x, b.y, b.z, b.w};
#pragma unroll
    for (int i = 0; i < 8; ++i) {
        _Float16 h = (_Float16)x[i];
        hv[i] = h;
        lv[i] = (_Float16)(x[i] - (float)h);
    }
}

// ---------------- shared K-loop: U tile via f16x2-split MFMA ------------------
// acc[mi][ni] covers c = mi*16+quad*4+reg, l = lcol0 + ni*16 + ln.
// FAST: depth-2 double-buffered B loads + distance-2 touch-prefetch.
// Touch regs are PERSISTENTLY LIVE ("+v" chain, sunk after the loop behind a
// vmcnt(0) drain) — R4's write-only dead-dest version let the allocator reuse
// the dest VGPR while the load was in flight -> async clobber -> crash.
// NOTE (R1): depth-3 register pipeline spilled (128-reg unified budget full:
// 64 arch + acc). NOTE (R3): 8 waves/EU (64-reg budget) spills catastrophically.
// 16 waves/CU @ 128 regs is the operating point.
// NOTE (R2): setprio around MFMAs cost +4% (lockstep waves, T5 null) — out.
template<bool FAST, int NI>
__device__ __forceinline__ void compute_U(const uint4* sA,
                                          const float* __restrict__ emb,
                                          const _Float16* __restrict__ tab,
                                          const int* __restrict__ trow, int lcol0,
                                          int lane, f32x4 acc[2][NI]) {
    int ln = lane & 15, quad = lane >> 4;
#pragma unroll
    for (int mi = 0; mi < 2; ++mi)
#pragma unroll
        for (int ni = 0; ni < NI; ++ni) acc[mi][ni] = (f32x4)0.0f;

    int arow0 = ln * 40;            // m = ln      (mi=0)
    int arow1 = (16 + ln) * 40;     // m = 16+ln   (mi=1)
    int key = ln & 7;
    int qo = quad * 8;

    if (FAST) {
        const _Float16* rp[NI];
#pragma unroll
        for (int ni = 0; ni < NI; ++ni) {
            int tok = trow[lcol0 + ni * 16 + ln];
            rp[ni] = tab + (size_t)tok * TROW;
        }
        // Touch-prefetch base: lane (quad,ln) owns token row quad*16+ln
        // (static recompute, not rp[quad] — dynamic index would go to scratch).
        // Across the wave: 4 quads x 16 ln = all 64 rows; hi+lo line each.
        const char* tbase = nullptr;
        int t0 = 0, t1 = 0;
        if (NI == 4) {
            int tokq = trow[quad * 16 + ln];
            tbase = (const char*)(tab + (size_t)tokq * TROW);
        }
        // depth-2 pipeline: hi half8 + lo half8 double-buffered, base+imm loads.
        half8_t bh[2][NI], bl[2][NI];
#pragma unroll
        for (int ni = 0; ni < NI; ++ni) {
            bh[0][ni] = *(const half8_t*)(rp[ni] + qo);
            bl[0][ni] = *(const half8_t*)(rp[ni] + 320 + qo);
        }
#pragma unroll
        for (int ks = 0; ks < 10; ++ks) {
            int cur = ks & 1, nxt = cur ^ 1;
            if (NI == 4 && ks < 8) {
                // touch iteration ks+2's two cache lines for this lane's token.
                // "+v": defs chain into next iteration's asm -> continuously
                // live registers, no reuse while loads are in flight.
                const char* pa = tbase + (ks + 2) * 64;
                const char* pb = pa + 640;
                asm volatile("global_load_dword %0, %2, off\n\t"
                             "global_load_dword %1, %3, off"
                             : "+v"(t0), "+v"(t1)
                             : "v"(pa), "v"(pb));
            }
            if (ks < 9) {
                int ko = (ks + 1) * 32 + qo;
#pragma unroll
                for (int ni = 0; ni < NI; ++ni) {
                    bh[nxt][ni] = *(const half8_t*)(rp[ni] + ko);
                    bl[nxt][ni] = *(const half8_t*)(rp[ni] + 320 + ko);
                }
            }
            int sp = (ks * 4 + quad) ^ key;
            half8_t ah[2], al[2];
            ah[0] = __builtin_bit_cast(half8_t, sA[arow0 + sp]);
            al[0] = __builtin_bit_cast(half8_t, sA[1280 + arow0 + sp]);
            ah[1] = __builtin_bit_cast(half8_t, sA[arow1 + sp]);
            al[1] = __builtin_bit_cast(half8_t, sA[1280 + arow1 + sp]);
#pragma unroll
            for (int mi = 0; mi < 2; ++mi)
#pragma unroll
                for (int ni = 0; ni < NI; ++ni) {
                    acc[mi][ni] = __builtin_amdgcn_mfma_f32_16x16x32_f16(ah[mi], bh[cur][ni], acc[mi][ni], 0, 0, 0);
                    acc[mi][ni] = __builtin_amdgcn_mfma_f32_16x16x32_f16(ah[mi], bl[cur][ni], acc[mi][ni], 0, 0, 0);
                    acc[mi][ni] = __builtin_amdgcn_mfma_f32_16x16x32_f16(al[mi], bh[cur][ni], acc[mi][ni], 0, 0, 0);
                }
        }
        if (NI == 4) {
            // Drain before the touch regs die: a pending VGPR write surviving
            // s_endpgm could corrupt a newly-scheduled wave's registers.
            asm volatile("s_waitcnt vmcnt(0)" ::: "memory");
            asm volatile("" :: "v"(t0), "v"(t1));
        }
    } else {
        const float* bp[NI];
#pragma unroll
        for (int ni = 0; ni < NI; ++ni) {
            int tok = trow[lcol0 + ni * 16 + ln];
            bp[ni] = emb + (size_t)tok * D;
        }
#pragma unroll 1
        for (int ks = 0; ks < 10; ++ks) {
            int kb = ks * 32 + qo;
            int ka = kb > 296 ? 296 : kb;
            int kb4 = kb + 4;
            int kbb = kb4 > 296 ? 296 : kb4;
            float4 b0[NI], b1[NI];
#pragma unroll
            for (int ni = 0; ni < NI; ++ni) {
                b0[ni] = *(const float4*)(bp[ni] + ka);
                b1[ni] = *(const float4*)(bp[ni] + kbb);
            }
            if (kb >= 296) {
                float4 z = make_float4(0.f, 0.f, 0.f, 0.f);
#pragma unroll
                for (int ni = 0; ni < NI; ++ni) {
                    if (kb >= 300) b0[ni] = z;
                    b1[ni] = z;
                }
            }
            int sp = (ks * 4 + quad) ^ key;
            half8_t ah[2], al[2];
            ah[0] = __builtin_bit_cast(half8_t, sA[arow0 + sp]);
            al[0] = __builtin_bit_cast(half8_t, sA[1280 + arow0 + sp]);
            ah[1] = __builtin_bit_cast(half8_t, sA[arow1 + sp]);
            al[1] = __builtin_bit_cast(half8_t, sA[1280 + arow1 + sp]);
            half8_t bh[NI], bl[NI];
#pragma unroll
            for (int ni = 0; ni < NI; ++ni) split8(b0[ni], b1[ni], bh[ni], bl[ni]);
#pragma unroll
            for (int mi = 0; mi < 2; ++mi)
#pragma unroll
                for (int ni = 0; ni < NI; ++ni) {
                    acc[mi][ni] = __builtin_amdgcn_mfma_f32_16x16x32_f16(ah[mi], bh[ni], acc[mi][ni], 0, 0, 0);
                    acc[mi][ni] = __builtin_amdgcn_mfma_f32_16x16x32_f16(ah[mi], bl[ni], acc[mi][ni], 0, 0, 0);
                    acc[mi][ni] = __builtin_amdgcn_mfma_f32_16x16x32_f16(al[mi], bh[ni], acc[mi][ni], 0, 0, 0);
                }
        }
    }
}

__device__ __forceinline__ float xmax4(float v) {
    v = fmaxf(v, __shfl_xor(v, 1)); v = fmaxf(v, __shfl_xor(v, 2));
    v = fmaxf(v, __shfl_xor(v, 4)); v = fmaxf(v, __shfl_xor(v, 8));
    return v;
}
__device__ __forceinline__ float xsum4(float v) {
    v += __shfl_xor(v, 1); v += __shfl_xor(v, 2);
    v += __shfl_xor(v, 4); v += __shfl_xor(v, 8);
    return v;
}

// ---------------- K2: target scores (wave-per-t; XCD-affinity swizzle) -------
// 1-D grid of 4096. xcd = wgid&7 (CP round-robin), b = xcd*8 + (wgid>>3)/64,
// tg = (wgid>>3)&63 -> each XCD serves 8 whole b's, tg-major (L2 locality).
template<bool FAST>
__global__ __launch_bounds__(256, 4) void k_scores(const int* __restrict__ targets,
                                                   const float* __restrict__ emb,
                                                   const _Float16* __restrict__ tab,
                                                   const _Float16* __restrict__ wsA,
                                                   float* __restrict__ wsScr) {
    __shared__ __align__(16) uint4 sA[A_U4];   // 40960 B -> 4 blocks/CU
    int wg = blockIdx.x;
    int xcd = wg & 7, rest = wg >> 3;
    int b = xcd * 8 + (rest >> 6);
    int tg = rest & 63;
    int tid = threadIdx.x;
    {
        const uint4* src = (const uint4*)(wsA + (size_t)b * A_HALF);
        for (int i = tid; i < A_U4; i += 256) sA[i] = src[i];
    }
    __syncthreads();

    int lane = tid & 63, wave = tid >> 6;
    int t = tg * 4 + wave;
    const int* trow = targets + ((size_t)b * T_ + t) * LT;

    f32x4 acc[2][4];
    compute_U<FAST, 4>(sA, emb, tab, trow, 0, lane, acc);

    // softmax over l per c, max over c, sum over l — all in-wave
    float score_l[4] = {0.f, 0.f, 0.f, 0.f};
#pragma unroll
    for (int mi = 0; mi < 2; ++mi)
#pragma unroll
        for (int r = 0; r < 4; ++r) {
            float m = fmaxf(fmaxf(acc[mi][0][r], acc[mi][1][r]),
                            fmaxf(acc[mi][2][r], acc[mi][3][r]));
            m = xmax4(m);                     // max over 64 l for this c
            float p[4], s = 0.f;
#pragma unroll
            for (int ni = 0; ni < 4; ++ni) { p[ni] = __expf(acc[mi][ni][r] - m); s += p[ni]; }
            s = xsum4(s);                     // denom over 64 l
            float rv = 1.0f / s;
#pragma unroll
            for (int ni = 0; ni < 4; ++ni) score_l[ni] = fmaxf(score_l[ni], p[ni] * rv);
        }
    float tot = 0.f;
#pragma unroll
    for (int ni = 0; ni < 4; ++ni) {
        float v = score_l[ni];                // fold max over c across quads
        v = fmaxf(v, __shfl_xor(v, 16));
        v = fmaxf(v, __shfl_xor(v, 32));
        tot += v;
    }
    tot = xsum4(tot);                         // sum over the 16 ln-columns
    if (lane == 0) wsScr[b * T_ + t] = tot;
}

// ---------------- K4: top-j select + recompute selected tile, L2-normalize ---
// One 256-thread block per (b, j). Wave 0 replays the top-k selection from
// wsScr (descending, lowest-index ties) while waves 1..3 stage the claim image.
template<bool FAST>
__global__ __launch_bounds__(256) void k_output(const int* __restrict__ targets,
                                                const float* __restrict__ emb,
                                                const _Float16* __restrict__ tab,
                                                const _Float16* __restrict__ wsA,
                                                const float* __restrict__ wsScr,
                                                float* __restrict__ out) {
    __shared__ __align__(16) uint4 sA[A_U4];
    __shared__ float sS[LC][4];
    __shared__ int sT;
    int b = blockIdx.y, j = blockIdx.x, tid = threadIdx.x;
    int lane = tid & 63, wave = tid >> 6;
    if (wave) {
        const uint4* src = (const uint4*)(wsA + (size_t)b * A_HALF);
        for (int i = tid - 64; i < A_U4; i += 192) sA[i] = src[i];
    } else {
        float v[4];
#pragma unroll
        for (int i = 0; i < 4; ++i) v[i] = wsScr[b * T_ + lane + 64 * i];
        int sel = 0;
        for (int r = 0; r <= j; ++r) {
            float bv = v[0]; int bi = lane;
#pragma unroll
            for (int i = 1; i < 4; ++i) {
                int idx = lane + 64 * i;
                if (v[i] > bv) { bv = v[i]; bi = idx; }
            }
            for (int off = 32; off > 0; off >>= 1) {
                float ov = __shfl_down(bv, off);
                int   oi = __shfl_down(bi, off);
                if (ov > bv || (ov == bv && oi < bi)) { bv = ov; bi = oi; }
            }
            bi = __shfl(bi, 0);
            sel = bi;
            if ((bi & 63) == lane) v[bi >> 6] = -1e30f;   // remove winner
        }
        if (lane == 0) sT = sel;
    }
    __syncthreads();

    int t = sT;
    const int* trow = targets + ((size_t)b * T_ + t) * LT;
    f32x4 acc[2][1];
    compute_U<FAST, 1>(sA, emb, tab, trow, wave * 16, lane, acc);

    int ln = lane & 15, quad = lane >> 4;
    // partial sum of squares over this wave's 16 l's, per c
#pragma unroll
    for (int mi = 0; mi < 2; ++mi)
#pragma unroll
        for (int r = 0; r < 4; ++r) {
            float v = acc[mi][0][r] * acc[mi][0][r];
            v = xsum4(v);                       // sum over the 16 ln-columns
            if (ln == 0) sS[mi * 16 + quad * 4 + r][wave] = v;
        }
    __syncthreads();

    float* obase = out + (size_t)(b * NSEL + j) * (LC * LT);
#pragma unroll
    for (int mi = 0; mi < 2; ++mi)
#pragma unroll
        for (int r = 0; r < 4; ++r) {
            int c = mi * 16 + quad * 4 + r;
            float ss = sS[c][0] + sS[c][1] + sS[c][2] + sS[c][3];
            float rinv = 1.0f / sqrtf(ss);
            obase[c * LT + wave * 16 + ln] = acc[mi][0][r] * rinv;
        }
}

extern "C" void kernel_launch(void* const* d_in, const int* in_sizes, int n_in,
                              void* d_out, int out_size, void* d_ws, size_t ws_size,
                              hipStream_t stream) {
    const int*   claim   = (const int*)d_in[0];
    const int*   targets = (const int*)d_in[1];
    const float* emb     = (const float*)d_in[2];
    // d_in[3] is n (=5), compile-time NSEL

    const size_t tabBytes = (size_t)VOCAB * TROW * sizeof(_Float16);   // 64 MB
    const size_t restBytes = (size_t)B_ * A_HALF * sizeof(_Float16)
                           + (size_t)B_ * T_ * sizeof(float)
                           + (size_t)B_ * NSEL * sizeof(int) + 256;
    bool fast = ws_size >= tabBytes + restBytes;   // deterministic per run

    char* p = (char*)d_ws;
    _Float16* tab = nullptr;
    if (fast) { tab = (_Float16*)p; p += tabBytes; }
    _Float16* wsA = (_Float16*)p; p += (size_t)B_ * A_HALF * sizeof(_Float16);
    float* wsScr = (float*)p;
    float* out   = (float*)d_out;

    int tableBlocks = fast ? (VOCAB / 4) : 0;
    k_prep<<<dim3(tableBlocks + 512), dim3(256), 0, stream>>>(claim, emb, tab, wsA, tableBlocks);
    if (fast) {
        k_scores<true><<<dim3(B_ * 64), dim3(256), 0, stream>>>(targets, emb, tab, wsA, wsScr);
        k_output<true><<<dim3(NSEL, B_), dim3(256), 0, stream>>>(targets, emb, tab, wsA, wsScr, out);
    } else {
        k_scores<false><<<dim3(B_ * 64), dim3(256), 0, stream>>>(targets, emb, tab, wsA, wsScr);
        k_output<false><<<dim3(NSEL, B_), dim3(256), 0, stream>>>(targets, emb, tab, wsA, wsScr, out);
    }
}

// Round 7
// 293.998 us; speedup vs baseline: 2.2856x; 1.8037x over previous
//
#include <hip/hip_runtime.h>
#include <hip/hip_bf16.h>

// Problem constants (fixed by the reference)
#define VOCAB 50000
#define D     300
#define B_    64
#define LC    32
#define T_    256
#define LT    64
#define NSEL  5

// A-image geometry: 32 rows x 40 slots (16B = 8 f16), k padded 300->320,
// slot s stored at s ^ (m&7) -> conflict-free ds_read_b128.
// hi: uint4[0..1280), lo: uint4[1280..2560). 40960 B per batch.
#define A_U4   2560
#define A_HALF 20480
// Table row: 10 x 128B blocks, each block = [32 hi halfs | 32 lo halfs] for one
// k-chunk of 32. One iteration's demand read per token row = ONE aligned 128B
// line (R5 post-mortem: serve rate is line-limited; the old hi|lo split at
// +640B made every iteration touch two 64B granules 640B apart).
#define TROW   640            // halfs per row (1280 B, 128B-aligned rows)

typedef _Float16 half8_t __attribute__((ext_vector_type(8)));
typedef float    f32x4   __attribute__((ext_vector_type(4)));

// ---------------- K0: merged prep: table (hi|lo f16) + claim images ----------
__global__ __launch_bounds__(256) void k_prep(const int* __restrict__ claim,
                                              const float* __restrict__ emb,
                                              _Float16* __restrict__ tab,
                                              _Float16* __restrict__ wsA,
                                              int tableBlocks) {
    int wave = threadIdx.x >> 6, lane = threadIdx.x & 63;
    if ((int)blockIdx.x < tableBlocks) {
        int r = blockIdx.x * 4 + wave;               // 12500*4 = 50000 rows
        const float* src = emb + (size_t)r * D;
        _Float16* d = tab + (size_t)r * TROW;
#pragma unroll
        for (int i = 0; i < 5; ++i) {
            int k = lane + i * 64;
            float x = (k < D) ? src[k] : 0.0f;
            _Float16 h = (_Float16)x;
            int blk = k >> 5, off = k & 31;          // 128B block, pos within
            d[blk * 64 + off]      = h;
            d[blk * 64 + 32 + off] = (_Float16)(x - (float)h);
        }
    } else {
        int row = (blockIdx.x - tableBlocks) * 4 + wave;   // 0..2047
        int b = row >> 5, m = row & 31;
        int tok = claim[row];
        const float* src = emb + (size_t)tok * D;
        _Float16* base = wsA + (size_t)b * A_HALF;
#pragma unroll
        for (int i = 0; i < 5; ++i) {
            int k = lane + i * 64;
            float x = (k < D) ? src[k] : 0.0f;
            _Float16 h = (_Float16)x;
            int sp = ((k >> 3) ^ (m & 7));
            int idx = (m * 40 + sp) * 8 + (k & 7);
            base[idx] = h;
            base[10240 + idx] = (_Float16)(x - (float)h);
        }
    }
}

// hi/lo split of a float4 pair into half8 hi and half8 lo (slow path only)
__device__ __forceinline__ void split8(const float4& a, const float4& b,
                                       half8_t& hv, half8_t& lv) {
    float x[8] = {a.x, a.y, a.z, a.w, b.x, b.y, b.z, b.w};
#pragma unroll
    for (int i = 0; i < 8; ++i) {
        _Float16 h = (_Float16)x[i];
        hv[i] = h;
        lv[i] = (_Float16)(x[i] - (float)h);
    }
}

// ---------------- shared K-loop: U tile via f16x2-split MFMA ------------------
// acc[mi][ni] covers c = mi*16+quad*4+reg, l = lcol0 + ni*16 + ln.
// FAST: depth-2 double-buffered B loads; per iteration each token row is one
// aligned 128B line ([hi32|lo32] block).
// Session ledger: R1 depth-3 spilled (128-reg unified budget is full at
// 64 arch + acc). R3 8 waves/EU spilled catastrophically — 16 waves/CU @
// 128 regs is THE operating point. R2: setprio cost +4% (lockstep, T5 null).
// R5: touch-prefetch at 3x MLP left throughput pinned at 3.3 TB/s while
// doubling FETCH -> serve-rate-limited; bytes are the only lever.
template<bool FAST, int NI>
__device__ __forceinline__ void compute_U(const uint4* sA,
                                          const float* __restrict__ emb,
                                          const _Float16* __restrict__ tab,
                                          const int* __restrict__ trow, int lcol0,
                                          int lane, f32x4 acc[2][NI]) {
    int ln = lane & 15, quad = lane >> 4;
#pragma unroll
    for (int mi = 0; mi < 2; ++mi)
#pragma unroll
        for (int ni = 0; ni < NI; ++ni) acc[mi][ni] = (f32x4)0.0f;

    int arow0 = ln * 40;            // m = ln      (mi=0)
    int arow1 = (16 + ln) * 40;     // m = 16+ln   (mi=1)
    int key = ln & 7;
    int qo = quad * 8;

    if (FAST) {
        const _Float16* rp[NI];
#pragma unroll
        for (int ni = 0; ni < NI; ++ni) {
            int tok = trow[lcol0 + ni * 16 + ln];
            rp[ni] = tab + (size_t)tok * TROW;
        }
        // depth-2 pipeline: hi half8 + lo half8 double-buffered. Block ks
        // holds k [ks*32, ks*32+32): hi at halfs [ks*64, +32), lo at +32.
        half8_t bh[2][NI], bl[2][NI];
#pragma unroll
        for (int ni = 0; ni < NI; ++ni) {
            bh[0][ni] = *(const half8_t*)(rp[ni] + qo);
            bl[0][ni] = *(const half8_t*)(rp[ni] + 32 + qo);
        }
#pragma unroll
        for (int ks = 0; ks < 10; ++ks) {
            int cur = ks & 1, nxt = cur ^ 1;
            if (ks < 9) {
                int ko = (ks + 1) * 64 + qo;
#pragma unroll
                for (int ni = 0; ni < NI; ++ni) {
                    bh[nxt][ni] = *(const half8_t*)(rp[ni] + ko);
                    bl[nxt][ni] = *(const half8_t*)(rp[ni] + 32 + ko);
                }
            }
            int sp = (ks * 4 + quad) ^ key;
            half8_t ah[2], al[2];
            ah[0] = __builtin_bit_cast(half8_t, sA[arow0 + sp]);
            al[0] = __builtin_bit_cast(half8_t, sA[1280 + arow0 + sp]);
            ah[1] = __builtin_bit_cast(half8_t, sA[arow1 + sp]);
            al[1] = __builtin_bit_cast(half8_t, sA[1280 + arow1 + sp]);
#pragma unroll
            for (int mi = 0; mi < 2; ++mi)
#pragma unroll
                for (int ni = 0; ni < NI; ++ni) {
                    acc[mi][ni] = __builtin_amdgcn_mfma_f32_16x16x32_f16(ah[mi], bh[cur][ni], acc[mi][ni], 0, 0, 0);
                    acc[mi][ni] = __builtin_amdgcn_mfma_f32_16x16x32_f16(ah[mi], bl[cur][ni], acc[mi][ni], 0, 0, 0);
                    acc[mi][ni] = __builtin_amdgcn_mfma_f32_16x16x32_f16(al[mi], bh[cur][ni], acc[mi][ni], 0, 0, 0);
                }
        }
    } else {
        const float* bp[NI];
#pragma unroll
        for (int ni = 0; ni < NI; ++ni) {
            int tok = trow[lcol0 + ni * 16 + ln];
            bp[ni] = emb + (size_t)tok * D;
        }
#pragma unroll 1
        for (int ks = 0; ks < 10; ++ks) {
            int kb = ks * 32 + qo;
            int ka = kb > 296 ? 296 : kb;
            int kb4 = kb + 4;
            int kbb = kb4 > 296 ? 296 : kb4;
            float4 b0[NI], b1[NI];
#pragma unroll
            for (int ni = 0; ni < NI; ++ni) {
                b0[ni] = *(const float4*)(bp[ni] + ka);
                b1[ni] = *(const float4*)(bp[ni] + kbb);
            }
            if (kb >= 296) {
                float4 z = make_float4(0.f, 0.f, 0.f, 0.f);
#pragma unroll
                for (int ni = 0; ni < NI; ++ni) {
                    if (kb >= 300) b0[ni] = z;
                    b1[ni] = z;
                }
            }
            int sp = (ks * 4 + quad) ^ key;
            half8_t ah[2], al[2];
            ah[0] = __builtin_bit_cast(half8_t, sA[arow0 + sp]);
            al[0] = __builtin_bit_cast(half8_t, sA[1280 + arow0 + sp]);
            ah[1] = __builtin_bit_cast(half8_t, sA[arow1 + sp]);
            al[1] = __builtin_bit_cast(half8_t, sA[1280 + arow1 + sp]);
            half8_t bh[NI], bl[NI];
#pragma unroll
            for (int ni = 0; ni < NI; ++ni) split8(b0[ni], b1[ni], bh[ni], bl[ni]);
#pragma unroll
            for (int mi = 0; mi < 2; ++mi)
#pragma unroll
                for (int ni = 0; ni < NI; ++ni) {
                    acc[mi][ni] = __builtin_amdgcn_mfma_f32_16x16x32_f16(ah[mi], bh[ni], acc[mi][ni], 0, 0, 0);
                    acc[mi][ni] = __builtin_amdgcn_mfma_f32_16x16x32_f16(ah[mi], bl[ni], acc[mi][ni], 0, 0, 0);
                    acc[mi][ni] = __builtin_amdgcn_mfma_f32_16x16x32_f16(al[mi], bh[ni], acc[mi][ni], 0, 0, 0);
                }
        }
    }
}

__device__ __forceinline__ float xmax4(float v) {
    v = fmaxf(v, __shfl_xor(v, 1)); v = fmaxf(v, __shfl_xor(v, 2));
    v = fmaxf(v, __shfl_xor(v, 4)); v = fmaxf(v, __shfl_xor(v, 8));
    return v;
}
__device__ __forceinline__ float xsum4(float v) {
    v += __shfl_xor(v, 1); v += __shfl_xor(v, 2);
    v += __shfl_xor(v, 4); v += __shfl_xor(v, 8);
    return v;
}

// ---------------- K2: target scores (wave-per-t; XCD-affinity swizzle) -------
// 1-D grid of 4096. xcd = wgid&7 (CP round-robin), b = xcd*8 + (wgid>>3)/64,
// tg = (wgid>>3)&63 -> each XCD serves 8 whole b's, tg-major (L2 locality).
template<bool FAST>
__global__ __launch_bounds__(256, 4) void k_scores(const int* __restrict__ targets,
                                                   const float* __restrict__ emb,
                                                   const _Float16* __restrict__ tab,
                                                   const _Float16* __restrict__ wsA,
                                                   float* __restrict__ wsScr) {
    __shared__ __align__(16) uint4 sA[A_U4];   // 40960 B -> 4 blocks/CU
    int wg = blockIdx.x;
    int xcd = wg & 7, rest = wg >> 3;
    int b = xcd * 8 + (rest >> 6);
    int tg = rest & 63;
    int tid = threadIdx.x;
    {
        const uint4* src = (const uint4*)(wsA + (size_t)b * A_HALF);
        for (int i = tid; i < A_U4; i += 256) sA[i] = src[i];
    }
    __syncthreads();

    int lane = tid & 63, wave = tid >> 6;
    int t = tg * 4 + wave;
    const int* trow = targets + ((size_t)b * T_ + t) * LT;

    f32x4 acc[2][4];
    compute_U<FAST, 4>(sA, emb, tab, trow, 0, lane, acc);

    // softmax over l per c, max over c, sum over l — all in-wave
    float score_l[4] = {0.f, 0.f, 0.f, 0.f};
#pragma unroll
    for (int mi = 0; mi < 2; ++mi)
#pragma unroll
        for (int r = 0; r < 4; ++r) {
            float m = fmaxf(fmaxf(acc[mi][0][r], acc[mi][1][r]),
                            fmaxf(acc[mi][2][r], acc[mi][3][r]));
            m = xmax4(m);                     // max over 64 l for this c
            float p[4], s = 0.f;
#pragma unroll
            for (int ni = 0; ni < 4; ++ni) { p[ni] = __expf(acc[mi][ni][r] - m); s += p[ni]; }
            s = xsum4(s);                     // denom over 64 l
            float rv = 1.0f / s;
#pragma unroll
            for (int ni = 0; ni < 4; ++ni) score_l[ni] = fmaxf(score_l[ni], p[ni] * rv);
        }
    float tot = 0.f;
#pragma unroll
    for (int ni = 0; ni < 4; ++ni) {
        float v = score_l[ni];                // fold max over c across quads
        v = fmaxf(v, __shfl_xor(v, 16));
        v = fmaxf(v, __shfl_xor(v, 32));
        tot += v;
    }
    tot = xsum4(tot);                         // sum over the 16 ln-columns
    if (lane == 0) wsScr[b * T_ + t] = tot;
}

// ---------------- K4: top-j select + recompute selected tile, L2-normalize ---
// One 256-thread block per (b, j). Wave 0 replays the top-k selection from
// wsScr (descending, lowest-index ties) while waves 1..3 stage the claim image.
template<bool FAST>
__global__ __launch_bounds__(256) void k_output(const int* __restrict__ targets,
                                                const float* __restrict__ emb,
                                                const _Float16* __restrict__ tab,
                                                const _Float16* __restrict__ wsA,
                                                const float* __restrict__ wsScr,
                                                float* __restrict__ out) {
    __shared__ __align__(16) uint4 sA[A_U4];
    __shared__ float sS[LC][4];
    __shared__ int sT;
    int b = blockIdx.y, j = blockIdx.x, tid = threadIdx.x;
    int lane = tid & 63, wave = tid >> 6;
    if (wave) {
        const uint4* src = (const uint4*)(wsA + (size_t)b * A_HALF);
        for (int i = tid - 64; i < A_U4; i += 192) sA[i] = src[i];
    } else {
        float v[4];
#pragma unroll
        for (int i = 0; i < 4; ++i) v[i] = wsScr[b * T_ + lane + 64 * i];
        int sel = 0;
        for (int r = 0; r <= j; ++r) {
            float bv = v[0]; int bi = lane;
#pragma unroll
            for (int i = 1; i < 4; ++i) {
                int idx = lane + 64 * i;
                if (v[i] > bv) { bv = v[i]; bi = idx; }
            }
            for (int off = 32; off > 0; off >>= 1) {
                float ov = __shfl_down(bv, off);
                int   oi = __shfl_down(bi, off);
                if (ov > bv || (ov == bv && oi < bi)) { bv = ov; bi = oi; }
            }
            bi = __shfl(bi, 0);
            sel = bi;
            if ((bi & 63) == lane) v[bi >> 6] = -1e30f;   // remove winner
        }
        if (lane == 0) sT = sel;
    }
    __syncthreads();

    int t = sT;
    const int* trow = targets + ((size_t)b * T_ + t) * LT;
    f32x4 acc[2][1];
    compute_U<FAST, 1>(sA, emb, tab, trow, wave * 16, lane, acc);

    int ln = lane & 15, quad = lane >> 4;
    // partial sum of squares over this wave's 16 l's, per c
#pragma unroll
    for (int mi = 0; mi < 2; ++mi)
#pragma unroll
        for (int r = 0; r < 4; ++r) {
            float v = acc[mi][0][r] * acc[mi][0][r];
            v = xsum4(v);                       // sum over the 16 ln-columns
            if (ln == 0) sS[mi * 16 + quad * 4 + r][wave] = v;
        }
    __syncthreads();

    float* obase = out + (size_t)(b * NSEL + j) * (LC * LT);
#pragma unroll
    for (int mi = 0; mi < 2; ++mi)
#pragma unroll
        for (int r = 0; r < 4; ++r) {
            int c = mi * 16 + quad * 4 + r;
            float ss = sS[c][0] + sS[c][1] + sS[c][2] + sS[c][3];
            float rinv = 1.0f / sqrtf(ss);
            obase[c * LT + wave * 16 + ln] = acc[mi][0][r] * rinv;
        }
}

extern "C" void kernel_launch(void* const* d_in, const int* in_sizes, int n_in,
                              void* d_out, int out_size, void* d_ws, size_t ws_size,
                              hipStream_t stream) {
    const int*   claim   = (const int*)d_in[0];
    const int*   targets = (const int*)d_in[1];
    const float* emb     = (const float*)d_in[2];
    // d_in[3] is n (=5), compile-time NSEL

    const size_t tabBytes = (size_t)VOCAB * TROW * sizeof(_Float16);   // 64 MB
    const size_t restBytes = (size_t)B_ * A_HALF * sizeof(_Float16)
                           + (size_t)B_ * T_ * sizeof(float)
                           + (size_t)B_ * NSEL * sizeof(int) + 256;
    bool fast = ws_size >= tabBytes + restBytes;   // deterministic per run

    char* p = (char*)d_ws;
    _Float16* tab = nullptr;
    if (fast) { tab = (_Float16*)p; p += tabBytes; }
    _Float16* wsA = (_Float16*)p; p += (size_t)B_ * A_HALF * sizeof(_Float16);
    float* wsScr = (float*)p;
    float* out   = (float*)d_out;

    int tableBlocks = fast ? (VOCAB / 4) : 0;
    k_prep<<<dim3(tableBlocks + 512), dim3(256), 0, stream>>>(claim, emb, tab, wsA, tableBlocks);
    if (fast) {
        k_scores<true><<<dim3(B_ * 64), dim3(256), 0, stream>>>(targets, emb, tab, wsA, wsScr);
        k_output<true><<<dim3(NSEL, B_), dim3(256), 0, stream>>>(targets, emb, tab, wsA, wsScr, out);
    } else {
        k_scores<false><<<dim3(B_ * 64), dim3(256), 0, stream>>>(targets, emb, tab, wsA, wsScr);
        k_output<false><<<dim3(NSEL, B_), dim3(256), 0, stream>>>(targets, emb, tab, wsA, wsScr, out);
    }
}